// Round 5
// baseline (105.658 us; speedup 1.0000x reference)
//
#include <hip/hip_runtime.h>
#include <hip/hip_fp16.h>
#include <math.h>

// B=8, CIN=COUT=128, H=W=Ho=Wo=64, K=9, stride=pad=dil=1, EPS=1e-4.
//
// Pipeline (2 launches):
//   prep_k  : blocks 0..511  -> xt[b][h][w][c] bf16 transpose (channel-last)
//             blocks 512..543 -> weight norm -> bf16 A-fragment order
//                                wb[k][c/8][cout][c%8]
//   dconv_k : 1024 blocks x 256 thr, block = 32 pixels x 128 couts.
//             TWO-PHASE structure (no per-tap serial chain):
//               phase1: gather ALL 9 taps -> colsS (76KB LDS), 72 independent
//                       dwordx4 loads/thread (max MLP), ONE barrier
//               phase2: 144 MFMA/wave straight from LDS, zero barriers
//             Geometry packed to 8 B/(tap,pixel) so LDS fits 2 blocks/CU.

typedef __attribute__((ext_vector_type(8))) short short8;   // 8 bf16 = 4 VGPRs
typedef __attribute__((ext_vector_type(4))) float floatx4;

static __device__ __forceinline__ unsigned int f2bf(float f) {
    unsigned int u = __float_as_uint(f);
    u += 0x7fffu + ((u >> 16) & 1u);          // round-to-nearest-even
    return u >> 16;
}
static __device__ __forceinline__ float bflo(unsigned int w) {
    return __uint_as_float(w << 16);
}
static __device__ __forceinline__ float bfhi(unsigned int w) {
    return __uint_as_float(w & 0xffff0000u);
}

// Fused transpose (blocks 0..511) + weight-norm (blocks 512..543)
__global__ void prep_k(const float* __restrict__ x, const float* __restrict__ w,
                       unsigned int* __restrict__ xt32, unsigned short* __restrict__ wb) {
    __shared__ float lds[128 * 65];
    const int tid = threadIdx.x;        // 256

    if (blockIdx.x < 512) {
        const int b = blockIdx.x >> 6, h = blockIdx.x & 63;
        const float* xp = x + (b * 128 * 64 + h) * 64;
        #pragma unroll 4
        for (int i = 0; i < 32; i++) {
            const int c = i * 4 + (tid >> 6);
            const int ww = tid & 63;
            lds[c * 65 + ww] = xp[c * 4096 + ww];
        }
        __syncthreads();
        unsigned int* xo = xt32 + blockIdx.x * 4096;   // [b][h][w][c/2]
        #pragma unroll 4
        for (int i = 0; i < 16; i++) {
            const int flat2 = i * 256 + tid;           // w*64 + cpair
            const int ww = flat2 >> 6, cp = flat2 & 63;
            const unsigned int lo = f2bf(lds[(2 * cp) * 65 + ww]);
            const unsigned int hi = f2bf(lds[(2 * cp + 1) * 65 + ww]);
            xo[flat2] = lo | (hi << 16);
        }
    } else {
        // weight norm: wave per cout o; lane holds c=2*lane, 2*lane+1
        const int o = (blockIdx.x - 512) * 4 + (tid >> 6);
        const int lane = tid & 63;
        const float* wo = w + o * 1152;                // [c][k]
        float v[18];
        #pragma unroll
        for (int i = 0; i < 18; i++) v[i] = wo[lane * 18 + i];
        float s[9];
        #pragma unroll
        for (int k = 0; k < 9; k++) s[k] = v[k] * v[k] + v[9 + k] * v[9 + k];
        #pragma unroll
        for (int d = 32; d >= 1; d >>= 1) {
            #pragma unroll
            for (int k = 0; k < 9; k++) s[k] += __shfl_xor(s[k], d, 64);
        }
        const int c0 = 2 * lane, c1 = c0 + 1;
        #pragma unroll
        for (int k = 0; k < 9; k++) {
            const float inv = 1.0f / (3.0f * sqrtf(s[k] + 0.0128f));   // 128*EPS
            wb[((k * 16 + (c0 >> 3)) * 128 + o) * 8 + (c0 & 7)] = (unsigned short)f2bf(v[k] * inv);
            wb[((k * 16 + (c1 >> 3)) * 128 + o) * 8 + (c1 & 7)] = (unsigned short)f2bf(v[9 + k] * inv);
        }
    }
}

static __device__ __forceinline__ uint4 combine4(const float w0, const float w1,
                                                 const float w2, const float w3,
                                                 const uint4 r0, const uint4 r1,
                                                 const uint4 r2, const uint4 r3) {
    uint4 pk;
    {
        const float lo = w0*bflo(r0.x) + w1*bflo(r1.x) + w2*bflo(r2.x) + w3*bflo(r3.x);
        const float hi = w0*bfhi(r0.x) + w1*bfhi(r1.x) + w2*bfhi(r2.x) + w3*bfhi(r3.x);
        pk.x = f2bf(lo) | (f2bf(hi) << 16);
    }
    {
        const float lo = w0*bflo(r0.y) + w1*bflo(r1.y) + w2*bflo(r2.y) + w3*bflo(r3.y);
        const float hi = w0*bfhi(r0.y) + w1*bfhi(r1.y) + w2*bfhi(r2.y) + w3*bfhi(r3.y);
        pk.y = f2bf(lo) | (f2bf(hi) << 16);
    }
    {
        const float lo = w0*bflo(r0.z) + w1*bflo(r1.z) + w2*bflo(r2.z) + w3*bflo(r3.z);
        const float hi = w0*bfhi(r0.z) + w1*bfhi(r1.z) + w2*bfhi(r2.z) + w3*bfhi(r3.z);
        pk.z = f2bf(lo) | (f2bf(hi) << 16);
    }
    {
        const float lo = w0*bflo(r0.w) + w1*bflo(r1.w) + w2*bflo(r2.w) + w3*bflo(r3.w);
        const float hi = w0*bfhi(r0.w) + w1*bfhi(r1.w) + w2*bfhi(r2.w) + w3*bfhi(r3.w);
        pk.w = f2bf(lo) | (f2bf(hi) << 16);
    }
    return pk;
}

__global__ __launch_bounds__(256, 2) void dconv_k(
    const unsigned short* __restrict__ xt, const float* __restrict__ off,
    const unsigned short* __restrict__ wb, float* __restrict__ out)
{
    // LDS: 2304 (packed taps) + 9*8448 (cols) = 78336 B -> 2 blocks/CU
    __shared__ uint2 tapP[288];                               // [k][p] packed geometry
    __shared__ alignas(16) unsigned short colsS[9][16 * 264]; // [k][c/8][32pix][8], +8el pad

    const int idx = blockIdx.x;
    const int b = idx & 7;                 // XCD-local batch
    const int ho = (idx >> 3) & 63;
    const int pix0 = (idx >> 9) * 32;
    const int tid = threadIdx.x;

    // ---- packed tap geometry: 288 = 9 taps x 32 pixels, 8 B each ----
    for (int t = tid; t < 288; t += 256) {
        const int k = t >> 5, p = t & 31;
        const int pw = pix0 + p;
        const int oidx = ((b * 18 + 2 * k) * 64 + ho) * 64 + pw;
        const float offy = off[oidx];
        const float offx = off[oidx + 4096];
        const float py = (float)(ho - 1 + (k / 3)) + offy;
        const float px = (float)(pw - 1 + (k % 3)) + offx;
        const float y0f = floorf(py), x0f = floorf(px);
        const float ly = py - y0f, lx = px - x0f;
        const unsigned int lyh = __half_as_ushort(__float2half_rn(ly));
        const unsigned int lxh = __half_as_ushort(__float2half_rn(lx));
        const int y0b = (int)y0f + 32, x0b = (int)x0f + 32;   // bias 32, fits u8
        uint2 pk;
        pk.x = lyh | (lxh << 16);
        pk.y = (unsigned int)(y0b & 0xFF) | ((unsigned int)(x0b & 0xFF) << 8);
        tapP[t] = pk;
    }
    __syncthreads();

    const int lane = tid & 63, wv = tid >> 6;
    const int quad = lane >> 4, l16 = lane & 15;
    const int g = tid & 15, prow = tid >> 4;      // gather: c-octet, pixel (0..15)
    const unsigned short* xb = xt + b * (64 * 64 * 128);
    const int wbase = wv * 32;                    // wave's cout base

    // ---- phase 1: gather ALL taps (72 independent dwordx4 loads/thread) ----
    for (int k = 0; k < 9; k++) {
        #pragma unroll
        for (int i = 0; i < 2; i++) {
            const int p = i * 16 + prow;
            const uint2 tp = tapP[k * 32 + p];
            const float ly = __half2float(__ushort_as_half((unsigned short)(tp.x & 0xffff)));
            const float lx = __half2float(__ushort_as_half((unsigned short)(tp.x >> 16)));
            const int y0 = (int)(tp.y & 0xFF) - 32;
            const int x0 = (int)((tp.y >> 8) & 0xFF) - 32;
            const int y1 = y0 + 1, x1 = x0 + 1;
            const float fy0 = (y0 >= 0 && y0 < 64) ? (1.0f - ly) : 0.0f;
            const float fy1 = (y1 >= 0 && y1 < 64) ? ly : 0.0f;
            const float fx0 = (x0 >= 0 && x0 < 64) ? (1.0f - lx) : 0.0f;
            const float fx1 = (x1 >= 0 && x1 < 64) ? lx : 0.0f;
            const int yc0 = min(max(y0, 0), 63), yc1 = min(max(y1, 0), 63);
            const int xc0 = min(max(x0, 0), 63), xc1 = min(max(x1, 0), 63);
            const uint4 r0 = *(const uint4*)(xb + ((yc0 * 64 + xc0) << 7) + g * 8);
            const uint4 r1 = *(const uint4*)(xb + ((yc0 * 64 + xc1) << 7) + g * 8);
            const uint4 r2 = *(const uint4*)(xb + ((yc1 * 64 + xc0) << 7) + g * 8);
            const uint4 r3 = *(const uint4*)(xb + ((yc1 * 64 + xc1) << 7) + g * 8);
            *(uint4*)&colsS[k][g * 264 + p * 8] =
                combine4(fy0 * fx0, fy0 * fx1, fy1 * fx0, fy1 * fx1, r0, r1, r2, r3);
        }
    }
    __syncthreads();

    // ---- phase 2: 144 MFMA per wave, zero barriers ----
    floatx4 acc0[2], acc1[2];
    #pragma unroll
    for (int t = 0; t < 2; t++) { acc0[t] = (floatx4)0.0f; acc1[t] = (floatx4)0.0f; }

    for (int k = 0; k < 9; k++) {
        const unsigned short* wk = wb + k * 16384;
        #pragma unroll
        for (int q = 0; q < 4; q++) {
            const int cgrp = q * 4 + quad;
            const short8 a0 = *(const short8*)(wk + (cgrp * 128 + wbase + l16) * 8);
            const short8 a1 = *(const short8*)(wk + (cgrp * 128 + wbase + 16 + l16) * 8);
            #pragma unroll
            for (int t = 0; t < 2; t++) {
                const short8 bf = *(const short8*)&colsS[k][cgrp * 264 + (t * 16 + l16) * 8];
                acc0[t] = __builtin_amdgcn_mfma_f32_16x16x32_bf16(a0, bf, acc0[t], 0, 0, 0);
                acc1[t] = __builtin_amdgcn_mfma_f32_16x16x32_bf16(a1, bf, acc1[t], 0, 0, 0);
            }
        }
    }

    // ---- epilogue: C/D layout col(=pixel)=lane&15, row(=cout)=quad*4+reg ----
    float* ob = out + b * 128 * 4096 + ho * 64 + pix0;
    #pragma unroll
    for (int t = 0; t < 2; t++) {
        const int pix = t * 16 + l16;
        #pragma unroll
        for (int r2 = 0; r2 < 4; r2++) {
            ob[(wbase + quad * 4 + r2) * 4096 + pix]      = acc0[t][r2];
            ob[(wbase + 16 + quad * 4 + r2) * 4096 + pix] = acc1[t][r2];
        }
    }
}

extern "C" void kernel_launch(void* const* d_in, const int* in_sizes, int n_in,
                              void* d_out, int out_size, void* d_ws, size_t ws_size,
                              hipStream_t stream) {
    const float* x   = (const float*)d_in[0];   // [8][128][64][64]
    const float* off = (const float*)d_in[1];   // [8][18][64][64]
    const float* w   = (const float*)d_in[2];   // [128][128][3][3]
    float* out = (float*)d_out;                 // [8][128][64][64]

    unsigned short* xt = (unsigned short*)d_ws;          // 4,194,304 bf16 = 8 MiB
    unsigned short* wbuf = xt + 8 * 64 * 64 * 128;       // 147,456 bf16

    hipLaunchKernelGGL(prep_k,  dim3(544),  dim3(256), 0, stream,
                       x, w, (unsigned int*)xt, wbuf);
    hipLaunchKernelGGL(dconv_k, dim3(1024), dim3(256), 0, stream, xt, off, wbuf, out);
}

// Round 6
// 99.274 us; speedup vs baseline: 1.0643x; 1.0643x over previous
//
#include <hip/hip_runtime.h>
#include <hip/hip_bf16.h>
#include <hip/hip_fp16.h>
#include <math.h>

// B=8, CIN=COUT=128, H=W=Ho=Wo=64, K=9, stride=pad=dil=1, EPS=1e-4.
//
// Pipeline (2 launches):
//   prep_k  : blocks 0..511  -> xt[b][h][w][c] bf16 transpose, XCD-ALIGNED
//             (b = blockIdx&7 so the XCD that writes xt[b] is the XCD whose
//             dconv blocks read it -> gathers hit the local 4MB L2)
//             blocks 512..543 -> weight norm -> bf16 A-fragment order
//                                wb[k][c/8][cout][c%8]
//   dconv_k : 1024 blocks x 256 thr, block = 32 pixels x 128 couts, 4 blocks/CU.
//             Per-tap pipeline (R4 structure): A-frags from L2 issued first,
//             corner prefetch for tap k+1 in flight across tap k's MFMAs,
//             cols double-buffered, one barrier per tap.
//             combine uses hw cvt_pk_bf16_f32; out stores non-temporal
//             (protect xt/weights L2 residency).

typedef __attribute__((ext_vector_type(8))) short short8;   // 8 bf16 = 4 VGPRs
typedef __attribute__((ext_vector_type(4))) float floatx4;

static __device__ __forceinline__ unsigned int f2bf(float f) {
    unsigned int u = __float_as_uint(f);
    u += 0x7fffu + ((u >> 16) & 1u);          // round-to-nearest-even
    return u >> 16;
}
static __device__ __forceinline__ float bflo(unsigned int w) {
    return __uint_as_float(w << 16);
}
static __device__ __forceinline__ float bfhi(unsigned int w) {
    return __uint_as_float(w & 0xffff0000u);
}
// hw v_cvt_pk_bf16_f32 pack (single instr vs ~10 VALU ops manual RNE)
static __device__ __forceinline__ unsigned int packbf2(float lo, float hi) {
    __hip_bfloat162 h = __float22bfloat162_rn(make_float2(lo, hi));
    unsigned int u;
    __builtin_memcpy(&u, &h, 4);
    return u;
}

// Fused transpose (blocks 0..511, XCD-aligned) + weight-norm (512..543)
__global__ void prep_k(const float* __restrict__ x, const float* __restrict__ w,
                       unsigned int* __restrict__ xt32, unsigned short* __restrict__ wb) {
    __shared__ float lds[128 * 65];
    const int tid = threadIdx.x;        // 256

    if (blockIdx.x < 512) {
        // XCD-aligned: b = blockIdx&7 matches dconv's swizzle
        const int b = blockIdx.x & 7, h = (blockIdx.x >> 3) & 63;
        const float* xp = x + (b * 128 * 64 + h) * 64;
        #pragma unroll 4
        for (int i = 0; i < 32; i++) {
            const int c = i * 4 + (tid >> 6);
            const int ww = tid & 63;
            lds[c * 65 + ww] = xp[c * 4096 + ww];
        }
        __syncthreads();
        unsigned int* xo = xt32 + (b * 64 + h) * 4096;   // [b][h][w][c/2]
        #pragma unroll 4
        for (int i = 0; i < 16; i++) {
            const int flat2 = i * 256 + tid;             // w*64 + cpair
            const int ww = flat2 >> 6, cp = flat2 & 63;
            xo[flat2] = packbf2(lds[(2 * cp) * 65 + ww], lds[(2 * cp + 1) * 65 + ww]);
        }
    } else {
        // weight norm: wave per cout o; lane holds c=2*lane, 2*lane+1
        const int o = (blockIdx.x - 512) * 4 + (tid >> 6);
        const int lane = tid & 63;
        const float* wo = w + o * 1152;                  // [c][k]
        float v[18];
        #pragma unroll
        for (int i = 0; i < 18; i++) v[i] = wo[lane * 18 + i];
        float s[9];
        #pragma unroll
        for (int k = 0; k < 9; k++) s[k] = v[k] * v[k] + v[9 + k] * v[9 + k];
        #pragma unroll
        for (int d = 32; d >= 1; d >>= 1) {
            #pragma unroll
            for (int k = 0; k < 9; k++) s[k] += __shfl_xor(s[k], d, 64);
        }
        const int c0 = 2 * lane, c1 = c0 + 1;
        #pragma unroll
        for (int k = 0; k < 9; k++) {
            const float inv = 1.0f / (3.0f * sqrtf(s[k] + 0.0128f));   // 128*EPS
            wb[((k * 16 + (c0 >> 3)) * 128 + o) * 8 + (c0 & 7)] = (unsigned short)f2bf(v[k] * inv);
            wb[((k * 16 + (c1 >> 3)) * 128 + o) * 8 + (c1 & 7)] = (unsigned short)f2bf(v[9 + k] * inv);
        }
    }
}

static __device__ __forceinline__ unsigned int bl1(const float w0, const float w1,
                                                   const float w2, const float w3,
                                                   unsigned int r0, unsigned int r1,
                                                   unsigned int r2, unsigned int r3) {
    const float lo = w0*bflo(r0) + w1*bflo(r1) + w2*bflo(r2) + w3*bflo(r3);
    const float hi = w0*bfhi(r0) + w1*bfhi(r1) + w2*bfhi(r2) + w3*bfhi(r3);
    return packbf2(lo, hi);
}

static __device__ __forceinline__ uint4 combine4(const float4 wvv,
                                                 const uint4 r0, const uint4 r1,
                                                 const uint4 r2, const uint4 r3) {
    uint4 pk;
    pk.x = bl1(wvv.x, wvv.y, wvv.z, wvv.w, r0.x, r1.x, r2.x, r3.x);
    pk.y = bl1(wvv.x, wvv.y, wvv.z, wvv.w, r0.y, r1.y, r2.y, r3.y);
    pk.z = bl1(wvv.x, wvv.y, wvv.z, wvv.w, r0.z, r1.z, r2.z, r3.z);
    pk.w = bl1(wvv.x, wvv.y, wvv.z, wvv.w, r0.w, r1.w, r2.w, r3.w);
    return pk;
}

__global__ __launch_bounds__(256, 4) void dconv_k(
    const unsigned short* __restrict__ xt, const float* __restrict__ off,
    const unsigned short* __restrict__ wb, float* __restrict__ out)
{
    // LDS: 4608 + 4608 + 2*8448 = 26112 B -> 4 blocks/CU
    __shared__ float4 tapw[288];                              // [k][p] corner weights
    __shared__ int4   tapi[288];                              // [k][p] corner offsets
    __shared__ alignas(16) unsigned short colsS[2][16 * 264]; // [buf][c/8][32pix][8], +8el pad

    const int idx = blockIdx.x;
    const int b = idx & 7;                 // XCD-local batch
    const int ho = (idx >> 3) & 63;
    const int pix0 = (idx >> 9) * 32;
    const int tid = threadIdx.x;

    // ---- tap geometry: 288 = 9 taps x 32 pixels ----
    for (int t = tid; t < 288; t += 256) {
        const int k = t >> 5, p = t & 31;
        const int pw = pix0 + p;
        const int oidx = ((b * 18 + 2 * k) * 64 + ho) * 64 + pw;
        const float offy = off[oidx];
        const float offx = off[oidx + 4096];
        const float py = (float)(ho - 1 + (k / 3)) + offy;
        const float px = (float)(pw - 1 + (k % 3)) + offx;
        const float y0f = floorf(py), x0f = floorf(px);
        const float ly = py - y0f, lx = px - x0f;
        const int y0 = (int)y0f, x0 = (int)x0f;
        const int y1 = y0 + 1, x1 = x0 + 1;
        const float vy0 = (y0 >= 0 && y0 < 64) ? 1.0f : 0.0f;
        const float vy1 = (y1 >= 0 && y1 < 64) ? 1.0f : 0.0f;
        const float vx0 = (x0 >= 0 && x0 < 64) ? 1.0f : 0.0f;
        const float vx1 = (x1 >= 0 && x1 < 64) ? 1.0f : 0.0f;
        const int yc0 = min(max(y0, 0), 63), yc1 = min(max(y1, 0), 63);
        const int xc0 = min(max(x0, 0), 63), xc1 = min(max(x1, 0), 63);
        tapw[t] = make_float4((1.0f - ly) * (1.0f - lx) * vy0 * vx0,
                              (1.0f - ly) * lx          * vy0 * vx1,
                              ly * (1.0f - lx)          * vy1 * vx0,
                              ly * lx                   * vy1 * vx1);
        tapi[t] = make_int4((yc0 * 64 + xc0) * 128, (yc0 * 64 + xc1) * 128,
                            (yc1 * 64 + xc0) * 128, (yc1 * 64 + xc1) * 128);
    }
    __syncthreads();

    const int lane = tid & 63, wv = tid >> 6;
    const int quad = lane >> 4, l16 = lane & 15;
    const int g = tid & 15, prow = tid >> 4;      // gather: c-octet, pixel (0..15)
    const unsigned short* xb = xt + b * (64 * 64 * 128);
    const int wbase = wv * 32;                    // wave's cout base

    floatx4 acc0[2], acc1[2];
    #pragma unroll
    for (int t = 0; t < 2; t++) { acc0[t] = (floatx4)0.0f; acc1[t] = (floatx4)0.0f; }

    // ---- prologue: gather tap 0 (each thread: 2 pixels x 4 corners) ----
    #pragma unroll
    for (int i = 0; i < 2; i++) {
        const int p = i * 16 + prow;
        const float4 wvv = tapw[p];
        const int4  iv  = tapi[p];
        const uint4 r0 = *(const uint4*)(xb + iv.x + g * 8);
        const uint4 r1 = *(const uint4*)(xb + iv.y + g * 8);
        const uint4 r2 = *(const uint4*)(xb + iv.z + g * 8);
        const uint4 r3 = *(const uint4*)(xb + iv.w + g * 8);
        *(uint4*)&colsS[0][g * 264 + p * 8] = combine4(wvv, r0, r1, r2, r3);
    }
    __syncthreads();

    // ---- tap loop: one barrier per tap ----
    for (int k = 0; k < 9; k++) {
        const int cur = k & 1;

        // A-fragments for tap k issued FIRST (their vmcnt completes without
        // draining the corner prefetch issued after them)
        const unsigned short* wk = wb + k * 16384;
        short8 a0[4], a1[4];
        #pragma unroll
        for (int q = 0; q < 4; q++) {
            const int cgrp = q * 4 + quad;
            a0[q] = *(const short8*)(wk + (cgrp * 128 + wbase + l16) * 8);
            a1[q] = *(const short8*)(wk + (cgrp * 128 + wbase + 16 + l16) * 8);
        }

        // corner prefetch for tap k+1
        uint4 r[2][4];
        if (k < 8) {
            #pragma unroll
            for (int i = 0; i < 2; i++) {
                const int p = i * 16 + prow;
                const int4 iv = tapi[(k + 1) * 32 + p];
                r[i][0] = *(const uint4*)(xb + iv.x + g * 8);
                r[i][1] = *(const uint4*)(xb + iv.y + g * 8);
                r[i][2] = *(const uint4*)(xb + iv.z + g * 8);
                r[i][3] = *(const uint4*)(xb + iv.w + g * 8);
            }
        }

        // MFMA: 16 per wave per tap
        #pragma unroll
        for (int q = 0; q < 4; q++) {
            const int cgrp = q * 4 + quad;
            #pragma unroll
            for (int t = 0; t < 2; t++) {
                const short8 bf = *(const short8*)&colsS[cur][cgrp * 264 + (t * 16 + l16) * 8];
                acc0[t] = __builtin_amdgcn_mfma_f32_16x16x32_bf16(a0[q], bf, acc0[t], 0, 0, 0);
                acc1[t] = __builtin_amdgcn_mfma_f32_16x16x32_bf16(a1[q], bf, acc1[t], 0, 0, 0);
            }
        }

        // combine + write tap k+1, single barrier
        if (k < 8) {
            #pragma unroll
            for (int i = 0; i < 2; i++) {
                const int p = i * 16 + prow;
                const float4 wvv = tapw[(k + 1) * 32 + p];
                *(uint4*)&colsS[cur ^ 1][g * 264 + p * 8] =
                    combine4(wvv, r[i][0], r[i][1], r[i][2], r[i][3]);
            }
            __syncthreads();
        }
    }

    // ---- epilogue: non-temporal stores (don't evict xt/weights from L2) ----
    float* ob = out + b * 128 * 4096 + ho * 64 + pix0;
    #pragma unroll
    for (int t = 0; t < 2; t++) {
        const int pix = t * 16 + l16;
        #pragma unroll
        for (int r2 = 0; r2 < 4; r2++) {
            __builtin_nontemporal_store(acc0[t][r2], &ob[(wbase + quad * 4 + r2) * 4096 + pix]);
            __builtin_nontemporal_store(acc1[t][r2], &ob[(wbase + 16 + quad * 4 + r2) * 4096 + pix]);
        }
    }
}

extern "C" void kernel_launch(void* const* d_in, const int* in_sizes, int n_in,
                              void* d_out, int out_size, void* d_ws, size_t ws_size,
                              hipStream_t stream) {
    const float* x   = (const float*)d_in[0];   // [8][128][64][64]
    const float* off = (const float*)d_in[1];   // [8][18][64][64]
    const float* w   = (const float*)d_in[2];   // [128][128][3][3]
    float* out = (float*)d_out;                 // [8][128][64][64]

    unsigned short* xt = (unsigned short*)d_ws;          // 4,194,304 bf16 = 8 MiB
    unsigned short* wbuf = xt + 8 * 64 * 64 * 128;       // 147,456 bf16

    hipLaunchKernelGGL(prep_k,  dim3(544),  dim3(256), 0, stream,
                       x, w, (unsigned int*)xt, wbuf);
    hipLaunchKernelGGL(dconv_k, dim3(1024), dim3(256), 0, stream, xt, off, wbuf, out);
}

// Round 7
// 98.782 us; speedup vs baseline: 1.0696x; 1.0050x over previous
//
#include <hip/hip_runtime.h>
#include <hip/hip_bf16.h>
#include <hip/hip_fp16.h>
#include <math.h>

// B=8, CIN=COUT=128, H=W=Ho=Wo=64, K=9, stride=pad=dil=1, EPS=1e-4.
//
// Pipeline (2 launches):
//   prep_k  : blocks 0..511  -> xt[b][h][w][c] bf16 transpose, XCD-aligned
//             blocks 512..543 -> weight norm -> bf16 A-fragment order
//                                wb[k][c/8][cout][c%8]
//   dconv_k : 512 blocks x 512 thr (8 waves), block = 64 pixels x 128 couts.
//             Each wave owns a 16-cout slice -> every weight byte read ONCE
//             per block (weight L2 traffic halved vs 32-pix blocks).
//             2 blocks/CU = 16 waves/CU. Packed 8-B tap geometry; cols
//             double-buffered; per-tap pipeline (A-frags from L2 issued first,
//             next tap's corners prefetched across MFMAs); NT out stores.

typedef __attribute__((ext_vector_type(8))) short short8;   // 8 bf16 = 4 VGPRs
typedef __attribute__((ext_vector_type(4))) float floatx4;

static __device__ __forceinline__ unsigned int f2bf(float f) {
    unsigned int u = __float_as_uint(f);
    u += 0x7fffu + ((u >> 16) & 1u);          // round-to-nearest-even
    return u >> 16;
}
static __device__ __forceinline__ float bflo(unsigned int w) {
    return __uint_as_float(w << 16);
}
static __device__ __forceinline__ float bfhi(unsigned int w) {
    return __uint_as_float(w & 0xffff0000u);
}
// hw v_cvt_pk_bf16_f32 pack
static __device__ __forceinline__ unsigned int packbf2(float lo, float hi) {
    __hip_bfloat162 h = __float22bfloat162_rn(make_float2(lo, hi));
    unsigned int u;
    __builtin_memcpy(&u, &h, 4);
    return u;
}

// Fused transpose (blocks 0..511, XCD-aligned) + weight-norm (512..543)
__global__ void prep_k(const float* __restrict__ x, const float* __restrict__ w,
                       unsigned int* __restrict__ xt32, unsigned short* __restrict__ wb) {
    __shared__ float lds[128 * 65];
    const int tid = threadIdx.x;        // 256

    if (blockIdx.x < 512) {
        const int b = blockIdx.x & 7, h = (blockIdx.x >> 3) & 63;
        const float* xp = x + (b * 128 * 64 + h) * 64;
        #pragma unroll 4
        for (int i = 0; i < 32; i++) {
            const int c = i * 4 + (tid >> 6);
            const int ww = tid & 63;
            lds[c * 65 + ww] = xp[c * 4096 + ww];
        }
        __syncthreads();
        unsigned int* xo = xt32 + (b * 64 + h) * 4096;   // [b][h][w][c/2]
        #pragma unroll 4
        for (int i = 0; i < 16; i++) {
            const int flat2 = i * 256 + tid;             // w*64 + cpair
            const int ww = flat2 >> 6, cp = flat2 & 63;
            xo[flat2] = packbf2(lds[(2 * cp) * 65 + ww], lds[(2 * cp + 1) * 65 + ww]);
        }
    } else {
        // weight norm: wave per cout o; lane holds c=2*lane, 2*lane+1
        const int o = (blockIdx.x - 512) * 4 + (tid >> 6);
        const int lane = tid & 63;
        const float* wo = w + o * 1152;                  // [c][k]
        float v[18];
        #pragma unroll
        for (int i = 0; i < 18; i++) v[i] = wo[lane * 18 + i];
        float s[9];
        #pragma unroll
        for (int k = 0; k < 9; k++) s[k] = v[k] * v[k] + v[9 + k] * v[9 + k];
        #pragma unroll
        for (int d = 32; d >= 1; d >>= 1) {
            #pragma unroll
            for (int k = 0; k < 9; k++) s[k] += __shfl_xor(s[k], d, 64);
        }
        const int c0 = 2 * lane, c1 = c0 + 1;
        #pragma unroll
        for (int k = 0; k < 9; k++) {
            const float inv = 1.0f / (3.0f * sqrtf(s[k] + 0.0128f));   // 128*EPS
            wb[((k * 16 + (c0 >> 3)) * 128 + o) * 8 + (c0 & 7)] = (unsigned short)f2bf(v[k] * inv);
            wb[((k * 16 + (c1 >> 3)) * 128 + o) * 8 + (c1 & 7)] = (unsigned short)f2bf(v[9 + k] * inv);
        }
    }
}

static __device__ __forceinline__ unsigned int bl1(const float w0, const float w1,
                                                   const float w2, const float w3,
                                                   unsigned int r0, unsigned int r1,
                                                   unsigned int r2, unsigned int r3) {
    const float lo = w0*bflo(r0) + w1*bflo(r1) + w2*bflo(r2) + w3*bflo(r3);
    const float hi = w0*bfhi(r0) + w1*bfhi(r1) + w2*bfhi(r2) + w3*bfhi(r3);
    return packbf2(lo, hi);
}

static __device__ __forceinline__ uint4 combine4(const float4 wvv,
                                                 const uint4 r0, const uint4 r1,
                                                 const uint4 r2, const uint4 r3) {
    uint4 pk;
    pk.x = bl1(wvv.x, wvv.y, wvv.z, wvv.w, r0.x, r1.x, r2.x, r3.x);
    pk.y = bl1(wvv.x, wvv.y, wvv.z, wvv.w, r0.y, r1.y, r2.y, r3.y);
    pk.z = bl1(wvv.x, wvv.y, wvv.z, wvv.w, r0.z, r1.z, r2.z, r3.z);
    pk.w = bl1(wvv.x, wvv.y, wvv.z, wvv.w, r0.w, r1.w, r2.w, r3.w);
    return pk;
}

// unpack 8-B tap record -> corner weights + corner row offsets (bf16 elems)
static __device__ __forceinline__ void tap_expand(const uint2 tp, float4& wvv, int4& iv) {
    const float ly = __half2float(__ushort_as_half((unsigned short)(tp.x & 0xffff)));
    const float lx = __half2float(__ushort_as_half((unsigned short)(tp.x >> 16)));
    const int y0 = (int)(tp.y & 0xFF) - 32;
    const int x0 = (int)((tp.y >> 8) & 0xFF) - 32;
    const int y1 = y0 + 1, x1 = x0 + 1;
    const float fy0 = (y0 >= 0 && y0 < 64) ? (1.0f - ly) : 0.0f;
    const float fy1 = (y1 >= 0 && y1 < 64) ? ly : 0.0f;
    const float fx0 = (x0 >= 0 && x0 < 64) ? (1.0f - lx) : 0.0f;
    const float fx1 = (x1 >= 0 && x1 < 64) ? lx : 0.0f;
    const int yc0 = min(max(y0, 0), 63), yc1 = min(max(y1, 0), 63);
    const int xc0 = min(max(x0, 0), 63), xc1 = min(max(x1, 0), 63);
    wvv = make_float4(fy0 * fx0, fy0 * fx1, fy1 * fx0, fy1 * fx1);
    iv = make_int4((yc0 * 64 + xc0) << 7, (yc0 * 64 + xc1) << 7,
                   (yc1 * 64 + xc0) << 7, (yc1 * 64 + xc1) << 7);
}

__global__ __launch_bounds__(512, 4) void dconv_k(
    const unsigned short* __restrict__ xt, const float* __restrict__ off,
    const unsigned short* __restrict__ wb, float* __restrict__ out)
{
    // LDS: 4608 (packed taps) + 2*16640 (cols) = 37888 B -> 2 blocks/CU
    __shared__ uint2 tapP[576];                               // [k][p] packed geometry
    __shared__ alignas(16) unsigned short colsS[2][16 * 520]; // [buf][c/8][64pix][8], +8el pad

    const int idx = blockIdx.x;
    const int b = idx & 7;                 // XCD-local batch
    const int ho = (idx >> 3) & 63;
    const int tid = threadIdx.x;           // 512

    // ---- packed tap geometry: 576 = 9 taps x 64 pixels, 8 B each ----
    for (int t = tid; t < 576; t += 512) {
        const int k = t >> 6, p = t & 63;
        const int oidx = ((b * 18 + 2 * k) * 64 + ho) * 64 + p;
        const float offy = off[oidx];
        const float offx = off[oidx + 4096];
        const float py = (float)(ho - 1 + (k / 3)) + offy;
        const float px = (float)(p - 1 + (k % 3)) + offx;
        const float y0f = floorf(py), x0f = floorf(px);
        uint2 pk;
        pk.x = (unsigned int)__half_as_ushort(__float2half_rn(py - y0f)) |
               ((unsigned int)__half_as_ushort(__float2half_rn(px - x0f)) << 16);
        pk.y = (unsigned int)(((int)y0f + 32) & 0xFF) |
               ((unsigned int)(((int)x0f + 32) & 0xFF) << 8);
        tapP[t] = pk;
    }
    __syncthreads();

    const int lane = tid & 63, wv = tid >> 6;   // 8 waves
    const int quad = lane >> 4, l16 = lane & 15;
    const int g = tid & 15, p0 = tid >> 4;      // gather cell: c-octet g, pixel p0 (0..31)
    const unsigned short* xb = xt + b * (64 * 64 * 128);
    const int obase = wv * 16;                  // wave's 16-cout slice

    floatx4 acc[4];
    #pragma unroll
    for (int t = 0; t < 4; t++) acc[t] = (floatx4)0.0f;

    // ---- prologue: gather tap 0 (each thread: pixels p0, p0+32) ----
    #pragma unroll
    for (int i = 0; i < 2; i++) {
        const int p = p0 + i * 32;
        float4 wvv; int4 iv;
        tap_expand(tapP[p], wvv, iv);
        const uint4 r0 = *(const uint4*)(xb + iv.x + g * 8);
        const uint4 r1 = *(const uint4*)(xb + iv.y + g * 8);
        const uint4 r2 = *(const uint4*)(xb + iv.z + g * 8);
        const uint4 r3 = *(const uint4*)(xb + iv.w + g * 8);
        *(uint4*)&colsS[0][g * 520 + p * 8] = combine4(wvv, r0, r1, r2, r3);
    }
    __syncthreads();

    // ---- tap loop: one barrier per tap ----
    for (int k = 0; k < 9; k++) {
        const int cur = k & 1;

        // A-fragments (16-cout slice) issued first: 4 coalesced 16B loads/lane
        const unsigned short* wk = wb + k * 16384;
        short8 a[4];
        #pragma unroll
        for (int q = 0; q < 4; q++) {
            const int cgrp = q * 4 + quad;
            a[q] = *(const short8*)(wk + (cgrp * 128 + obase + l16) * 8);
        }

        // corner prefetch for tap k+1 (8 independent dwordx4)
        uint4 r[2][4];
        float4 wvv[2]; int4 ivd[2];
        if (k < 8) {
            #pragma unroll
            for (int i = 0; i < 2; i++) {
                const int p = p0 + i * 32;
                tap_expand(tapP[(k + 1) * 64 + p], wvv[i], ivd[i]);
                r[i][0] = *(const uint4*)(xb + ivd[i].x + g * 8);
                r[i][1] = *(const uint4*)(xb + ivd[i].y + g * 8);
                r[i][2] = *(const uint4*)(xb + ivd[i].z + g * 8);
                r[i][3] = *(const uint4*)(xb + ivd[i].w + g * 8);
            }
        }

        // MFMA: 16 per wave per tap (4 k-steps x 4 pixel-tiles)
        #pragma unroll
        for (int q = 0; q < 4; q++) {
            const int cgrp = q * 4 + quad;
            #pragma unroll
            for (int t = 0; t < 4; t++) {
                const short8 bf = *(const short8*)&colsS[cur][cgrp * 520 + (t * 16 + l16) * 8];
                acc[t] = __builtin_amdgcn_mfma_f32_16x16x32_bf16(a[q], bf, acc[t], 0, 0, 0);
            }
        }

        // combine + write tap k+1 into the other buffer, single barrier
        if (k < 8) {
            #pragma unroll
            for (int i = 0; i < 2; i++) {
                const int p = p0 + i * 32;
                *(uint4*)&colsS[cur ^ 1][g * 520 + p * 8] =
                    combine4(wvv[i], r[i][0], r[i][1], r[i][2], r[i][3]);
            }
            __syncthreads();
        }
    }

    // ---- epilogue: C/D col(=pixel)=lane&15, row(=cout)=quad*4+reg; NT stores ----
    float* ob = out + b * 128 * 4096 + ho * 64;
    #pragma unroll
    for (int t = 0; t < 4; t++) {
        const int pix = t * 16 + l16;
        #pragma unroll
        for (int r2 = 0; r2 < 4; r2++) {
            __builtin_nontemporal_store(acc[t][r2],
                &ob[(obase + quad * 4 + r2) * 4096 + pix]);
        }
    }
}

extern "C" void kernel_launch(void* const* d_in, const int* in_sizes, int n_in,
                              void* d_out, int out_size, void* d_ws, size_t ws_size,
                              hipStream_t stream) {
    const float* x   = (const float*)d_in[0];   // [8][128][64][64]
    const float* off = (const float*)d_in[1];   // [8][18][64][64]
    const float* w   = (const float*)d_in[2];   // [128][128][3][3]
    float* out = (float*)d_out;                 // [8][128][64][64]

    unsigned short* xt = (unsigned short*)d_ws;          // 4,194,304 bf16 = 8 MiB
    unsigned short* wbuf = xt + 8 * 64 * 64 * 128;       // 147,456 bf16

    hipLaunchKernelGGL(prep_k,  dim3(544), dim3(256), 0, stream,
                       x, w, (unsigned int*)xt, wbuf);
    hipLaunchKernelGGL(dconv_k, dim3(512), dim3(512), 0, stream, xt, off, wbuf, out);
}